// Round 8
// baseline (1554.398 us; speedup 1.0000x reference)
//
#include <hip/hip_runtime.h>

#define SEQ 2048
#define HID 1024
#define SZ (SEQ * HID)            // elements per theta level
#define NPH 24                    // 1 PRE0 + 16 sweeps + 7 theta

#define F_SHIFT 1                 // A row s reads row s-1 (s==0 -> state row)
#define F_RAW   2                 // outF gets pre-tanh value (PRE0 stage)
#define F_TAIL  4                 // row SEQ-1 also written to out[8*SZ..] (hT)

typedef unsigned short u16;
typedef unsigned int u32;
typedef __attribute__((ext_vector_type(8))) short short8;
typedef __attribute__((ext_vector_type(4))) float floatx4;

__device__ __forceinline__ u16 f2b(float v) {
    unsigned x = __builtin_bit_cast(unsigned, v);
    unsigned r = (x + 0x7fffu + ((x >> 16) & 1u)) >> 16;
    return (u16)r;
}

__device__ __forceinline__ float ftanh(float x) {
    float e = __expf(2.0f * x);
    return 1.0f - 2.0f * __builtin_amdgcn_rcpf(e + 1.0f);
}

__device__ __forceinline__ void glds16(const void* g, void* l) {
    __builtin_amdgcn_global_load_lds(
        (const __attribute__((address_space(1))) u32*)g,
        (__attribute__((address_space(3))) u32*)l, 16, 0, 0);
}

// relaxed agent-scope polls (sc-bypass -> always fresh, no livelock), then one
// acquire load to invalidate L1/XCD-L2 before data reads.  Bounded: on valve
// expiry we proceed (worst case wrong answer, never a hang).
__device__ __forceinline__ void spinwait16(int* f) {
    int it = 0;
    while (__hip_atomic_load(f, __ATOMIC_RELAXED, __HIP_MEMORY_SCOPE_AGENT) < 16) {
        __builtin_amdgcn_s_sleep(8);
        if (++it > (1 << 20)) break;   // ~0.3 s valve
    }
    (void)__hip_atomic_load(f, __ATOMIC_ACQUIRE, __HIP_MEMORY_SCOPE_AGENT);
}

// converts f32 inputs to bf16 workspaces + zeroes the phase flags
__global__ void cvt_all(const float* __restrict__ W_ih, const float* __restrict__ W_hh,
                        const float* __restrict__ x, const float* __restrict__ state,
                        u16* __restrict__ Wihb, u16* __restrict__ Whhb,
                        u16* __restrict__ Xb, u16* __restrict__ Sb, int* __restrict__ cnt) {
    int i = blockIdx.x * 256 + threadIdx.x;
    const int M = HID * HID;
    if (i < M)                 { Wihb[i] = f2b(W_ih[i]); return; }
    i -= M;
    if (i < M)                 { Whhb[i] = f2b(W_hh[i]); return; }
    i -= M;
    if (i < SEQ * HID)         { Xb[i] = f2b(x[i]); return; }
    i -= SEQ * HID;
    if (i < HID)               { Sb[i] = f2b(state[i]); return; }
    i -= HID;
    if (i < NPH * 32)          { cnt[i] = 0; }
}

// ---------------------------------------------------------------------------
// Round-14: PERSISTENT MEGAKERNEL.  Evidence (rounds 3-7): per-dispatch time
// ~15.3 us is invariant to BK, LDS traffic, stagger, occupancy -> dominated
// by the per-dispatch envelope (launch gap + kernel-boundary cache flush +
// ramp/tail), not the inner loop.  Fuse all 24 GEMM phases into one launch:
//  * block keeps tile (by,bx) for all phases (inner body = verified round-3
//    384us tile: BK=128 ring-2 full-drain, 16-granule XOR swizzle, XCD-
//    chunked swizzle, addF reg prefetch, setprio; stagger removed -> round-3
//    numerics bit-exact).
//  * cross-phase dep via row-block flags: phase p tile (by,.) waits until
//    rows {by-1,by,by+1} finished phase p-1.  by-1: F_SHIFT RAW edge.
//    by+1: WAR edge (ping-pong buffer written at p was read at p-1 by row
//    by+1's shifted A-tile).  Release: syncthreads (vmcnt drained) +
//    threadfence (L2 writeback) + agent release add.  Acquire: relaxed
//    agent polls + one acquire load (cache inv).
//  * co-residency by resources: 64KB LDS + launch_bounds(256,2) -> exactly
//    2 blocks/CU, 512 blocks = 256 CUs x 2.  Phase 0 has no wait.
//  * anti-hang valve on every spin.
// ---------------------------------------------------------------------------
__launch_bounds__(256, 2)
__global__ void mega(const u16* __restrict__ Xb, const u16* __restrict__ Wihb,
                     const u16* __restrict__ Whhb, u16* __restrict__ H0,
                     u16* __restrict__ H1, float* __restrict__ PRE0,
                     const u16* __restrict__ Sb, const float* __restrict__ internal,
                     const float* __restrict__ b_ih, const float* __restrict__ b_hh,
                     float* __restrict__ out, int* __restrict__ cnt) {
    __shared__ u16 As[2][64 * 128];   // 2 x 16 KB
    __shared__ u16 Bs[2][64 * 128];   // 2 x 16 KB
    const int tid  = threadIdx.x;
    const int lane = tid & 63, w = tid >> 6;
    const int quad = lane >> 4, l16 = lane & 15;
    const int wr = w >> 1, wc = w & 1;                 // 2x2 wave grid

    const int hw = blockIdx.y * 16 + blockIdx.x;       // hardware linear id
    const int lg = (hw & 7) * 64 + (hw >> 3);          // XCD-chunked remap
    const int bx = lg & 15, by = lg >> 4;
    const int colBase = bx * 64, rowBase = by * 64;

    const int ric = lane >> 4;            // row within chunk (0..3)
    const int g16 = lane & 15;            // lane's LDS granule position
    int lrr[4], ggr[4], loff[4];
    #pragma unroll
    for (int j = 0; j < 4; j++) {
        const int c = 4 * w + j;          // chunk 0..15
        lrr[j]  = c * 4 + ric;            // local row 0..63
        ggr[j]  = (g16 ^ (lrr[j] & 15)) * 8;   // pre-swizzled source granule
        loff[j] = c * 512;                // chunk c -> u16 offset (1 KB)
    }

    const u16* cur = H0;
    u16* nxt = H1;

    #pragma unroll 1
    for (int p = 0; p < NPH; p++) {
        // ---- phase parameters ----
        const u16* Ap; const u16* Bw; const float* addF; const float* bb;
        float* outF; u16* outB; int flags;
        if (p == 0) {
            Ap = Xb; Bw = Wihb; addF = internal; bb = b_ih;
            outF = PRE0; outB = H0; flags = F_RAW;
        } else if (p <= 16) {
            Ap = cur; Bw = Whhb; addF = PRE0; bb = nullptr;
            outF = (p == 16) ? out : nullptr; outB = nxt;
            flags = F_SHIFT | ((p == 16) ? F_TAIL : 0);
        } else {
            const int th = p - 16;
            Ap = cur; Bw = Whhb; addF = internal + (size_t)th * SZ; bb = b_ih;
            outF = out + (size_t)th * SZ; outB = (th < 7) ? nxt : nullptr;
            flags = 0;
        }

        // ---- dependency wait (rows by-1, by, by+1 at phase p-1) ----
        if (p > 0) {
            if (tid == 0) {
                int* base = cnt + (p - 1) * 32;
                spinwait16(base + by);
                if (by > 0)  spinwait16(base + by - 1);
                if (by < 31) spinwait16(base + by + 1);
            }
            __syncthreads();
        }

        // ---- staging pointers for this phase ----
        const u16* aP[4]; const u16* bP[4];
        #pragma unroll
        for (int j = 0; j < 4; j++) {
            const int gr = rowBase + lrr[j];
            const u16* ap;
            if (flags & F_SHIFT) ap = (gr == 0) ? Sb : Ap + (size_t)(gr - 1) * HID;
            else                 ap = Ap + (size_t)gr * HID;
            aP[j] = ap + ggr[j];
            bP[j] = Bw + (size_t)(colBase + lrr[j]) * HID + ggr[j];
        }

        // ---- epilogue addF prefetch (hides under prologue) ----
        float ad[2][2][4];
        #pragma unroll
        for (int mi = 0; mi < 2; mi++)
            #pragma unroll
            for (int ni = 0; ni < 2; ni++) {
                const int col = colBase + wc * 32 + ni * 16 + l16;
                #pragma unroll
                for (int i = 0; i < 4; i++) {
                    const int row = rowBase + wr * 32 + mi * 16 + quad * 4 + i;
                    ad[mi][ni][i] = addF[(size_t)row * HID + col];
                }
            }

        // ---- prologue: stage K-chunk 0 into buffer 0 ----
        #pragma unroll
        for (int j = 0; j < 4; j++) {
            glds16(aP[j], &As[0][loff[j]]);
            glds16(bP[j], &Bs[0][loff[j]]);
        }

        floatx4 acc[2][2];
        #pragma unroll
        for (int mi = 0; mi < 2; mi++)
            #pragma unroll
            for (int ni = 0; ni < 2; ni++)
                acc[mi][ni] = (floatx4){0.f, 0.f, 0.f, 0.f};

        #pragma unroll
        for (int kt = 0; kt < 8; kt++) {
            __syncthreads();               // drain: chunk kt visible; ring WAR safe

            if (kt + 1 < 8) {
                const int b = (kt + 1) & 1;
                #pragma unroll
                for (int j = 0; j < 4; j++) {
                    glds16(aP[j] + (kt + 1) * 128, &As[b][loff[j]]);
                    glds16(bP[j] + (kt + 1) * 128, &Bs[b][loff[j]]);
                }
            }

            const u16* Ab = &As[kt & 1][0];
            const u16* Bb = &Bs[kt & 1][0];
            __builtin_amdgcn_s_setprio(1);
            #pragma unroll
            for (int kk = 0; kk < 4; kk++) {
                short8 af[2], bf[2];
                #pragma unroll
                for (int mi = 0; mi < 2; mi++) {
                    const int r = wr * 32 + mi * 16 + l16;
                    const int f = kk * 4 + quad;
                    af[mi] = *(const short8*)&Ab[r * 128 + ((f ^ (r & 15)) * 8)];
                }
                #pragma unroll
                for (int ni = 0; ni < 2; ni++) {
                    const int r = wc * 32 + ni * 16 + l16;
                    const int f = kk * 4 + quad;
                    bf[ni] = *(const short8*)&Bb[r * 128 + ((f ^ (r & 15)) * 8)];
                }
                #pragma unroll
                for (int mi = 0; mi < 2; mi++)
                    #pragma unroll
                    for (int ni = 0; ni < 2; ni++)
                        acc[mi][ni] = __builtin_amdgcn_mfma_f32_16x16x32_bf16(
                            af[mi], bf[ni], acc[mi][ni], 0, 0, 0);
            }
            __builtin_amdgcn_s_setprio(0);
        }

        // ---- epilogue (identical mapping to rounds 1-13, verified) ----
        #pragma unroll
        for (int mi = 0; mi < 2; mi++) {
            #pragma unroll
            for (int ni = 0; ni < 2; ni++) {
                const int col = colBase + wc * 32 + ni * 16 + l16;
                #pragma unroll
                for (int i = 0; i < 4; i++) {
                    const int row = rowBase + wr * 32 + mi * 16 + quad * 4 + i;
                    const size_t idx = (size_t)row * HID + col;
                    float v = acc[mi][ni][i];
                    v += ad[mi][ni][i];
                    if (bb) v += bb[col] + b_hh[col];
                    const float t = ftanh(v);
                    if (outF) outF[idx] = (flags & F_RAW) ? v : t;
                    if (outB) outB[idx] = f2b(t);
                    if ((flags & F_TAIL) && row == SEQ - 1)
                        outF[(size_t)8 * SZ + col] = t;
                }
            }
        }

        // ---- release: stores drained (syncthreads) -> L2 writeback -> post ----
        __syncthreads();                   // emits vmcnt(0) drain before barrier
        if (tid == 0) {
            __threadfence();               // agent fence: L2 writeback to L3
            __hip_atomic_fetch_add(cnt + p * 32 + by, 1,
                                   __ATOMIC_RELEASE, __HIP_MEMORY_SCOPE_AGENT);
        }

        if (p >= 1) { const u16* t = cur; cur = nxt; nxt = (u16*)t; }
    }
}

extern "C" void kernel_launch(void* const* d_in, const int* in_sizes, int n_in,
                              void* d_out, int out_size, void* d_ws, size_t ws_size,
                              hipStream_t stream) {
    const float* x        = (const float*)d_in[0];   // [1,2048,1024]
    const float* internal = (const float*)d_in[1];   // [8,2048,1024]
    const float* state    = (const float*)d_in[2];   // [1,1,1024]
    const float* W_ih     = (const float*)d_in[3];   // [1024,1024]
    const float* W_hh     = (const float*)d_in[4];   // [1024,1024]
    const float* b_ih     = (const float*)d_in[5];   // [1024]
    const float* b_hh     = (const float*)d_in[6];   // [1024]
    float* out = (float*)d_out;
    char* ws = (char*)d_ws;

    u16*   Wihb = (u16*)(ws);                         // 2 MB [1024][1024]
    u16*   Whhb = (u16*)(ws + ((size_t)2 << 20));     // 2 MB
    u16*   Xb   = (u16*)(ws + ((size_t)4 << 20));     // 4 MB [2048][1024]
    u16*   H0   = (u16*)(ws + ((size_t)8 << 20));     // 4 MB [2048][1024]
    u16*   H1   = (u16*)(ws + ((size_t)12 << 20));    // 4 MB
    float* PRE0 = (float*)(ws + ((size_t)16 << 20));  // 8 MB f32
    u16*   Sb   = (u16*)(ws + ((size_t)24 << 20));    // 2 KB state bf16
    int*   cnt  = (int*)(ws + ((size_t)24 << 20) + 4096);  // 3 KB phase flags

    const int ncvt = 2 * HID * HID + SEQ * HID + HID + NPH * 32;
    cvt_all<<<(ncvt + 255) / 256, 256, 0, stream>>>(
        W_ih, W_hh, x, state, Wihb, Whhb, Xb, Sb, cnt);

    dim3 grid(HID / 64, SEQ / 64);   // (16, 32) = 512 blocks = 2/CU exactly
    mega<<<grid, 256, 0, stream>>>(Xb, Wihb, Whhb, H0, H1, PRE0, Sb,
                                   internal, b_ih, b_hh, out, cnt);
}